// Round 9
// baseline (3851.728 us; speedup 1.0000x reference)
//
#include <hip/hip_runtime.h>
#include <hip/hip_bf16.h>

#define B    256
#define S    192
#define F    64
#define HD   1024
#define PRED 48
#define TSTART (S - 1 - PRED)   // 143

typedef __attribute__((ext_vector_type(8))) short short8;
typedef __attribute__((ext_vector_type(4))) float f32x4;
typedef unsigned int u32;

static __device__ __forceinline__ short f2bf(float f) {
    __hip_bfloat16 h = __float2bfloat16(f);
    return *reinterpret_cast<short*>(&h);
}
static __device__ __forceinline__ f32x4 mfma16(short8 a, short8 b, f32x4 c) {
    return __builtin_amdgcn_mfma_f32_16x16x32_bf16(a, b, c, 0, 0, 0);
}
static __device__ __forceinline__ short8 ld8(const short* p) {
    return *reinterpret_cast<const short8*>(p);
}

// ---------------------------------------------------------------------------
// prep kernels
// ---------------------------------------------------------------------------
// fold: Wfold[f][n] = sum_k Wh[f][k] * Wih0[k][n]; 256 blocks (1 f each).
__global__ void fold_kernel(const float* __restrict__ Wh,
                            const float* __restrict__ Wih0,
                            float* __restrict__ Wfold) {
    const int n = (blockIdx.x & 3) * 256 + threadIdx.x;
    const int f = blockIdx.x >> 2;
    float a = 0.f;
#pragma unroll 16
    for (int k = 0; k < HD; ++k)
        a += Wh[f * HD + k] * Wih0[(size_t)k * HD + n];
    Wfold[f * HD + n] = a;
}

__global__ void bias_kernel(const float* __restrict__ bh,
                            const float* __restrict__ Wih0,
                            const float* __restrict__ bih,
                            const float* __restrict__ bhh,
                            float* __restrict__ bf0,
                            float* __restrict__ bf1) {
    const int n = blockIdx.x * 256 + threadIdx.x;
    float a = 0.f;
#pragma unroll 8
    for (int k = 0; k < HD; ++k) a += bh[k] * Wih0[(size_t)k * HD + n];
    bf0[n] = a + bih[n] + bhh[n];
    bf1[n] = bih[HD + n] + bhh[HD + n];
}

__global__ void transpose_cast(const float* __restrict__ src,
                               short* __restrict__ dst, int K, int N) {
    __shared__ float tile[64][65];
    const int nk = K >> 6;
    const int bk = blockIdx.x % nk;
    const int bn = blockIdx.x / nk;
    const int i  = threadIdx.x;
    {
        const int c4 = (i & 15) * 4;
        for (int it = 0; it < 4; ++it) {
            const int k = (i >> 4) + it * 16;
            const float4 v = *reinterpret_cast<const float4*>(
                &src[(size_t)(bk * 64 + k) * N + bn * 64 + c4]);
            tile[k][c4 + 0] = v.x; tile[k][c4 + 1] = v.y;
            tile[k][c4 + 2] = v.z; tile[k][c4 + 3] = v.w;
        }
    }
    __syncthreads();
    {
        const int n  = i >> 2;
        const int kb = (i & 3) * 16;
        short* dp = &dst[(size_t)(bn * 64 + n) * K + bk * 64 + kb];
#pragma unroll
        for (int j = 0; j < 16; ++j) dp[j] = f2bf(tile[kb + j][n]);
    }
}

__global__ void xcast(const float* __restrict__ x, short* __restrict__ xb) {
    const size_t i = ((size_t)blockIdx.x * 256 + threadIdx.x) * 4;
    const float4 v = *reinterpret_cast<const float4*>(&x[i]);
    short4 o;
    o.x = f2bf(v.x); o.y = f2bf(v.y); o.z = f2bf(v.z); o.w = f2bf(v.w);
    *reinterpret_cast<short4*>(&xb[i]) = o;
}

// ---------------------------------------------------------------------------
// stageA: 32 rows x 1024 bf16 -> 64KB LDS, XOR-swizzled (R8-proven).
// ---------------------------------------------------------------------------
static __device__ __forceinline__ void stageA(char* lds, const short* __restrict__ src,
                                              int row0) {
    const int tid = threadIdx.x;
#pragma unroll
    for (int it = 0; it < 8; ++it) {
        const int c = it * 512 + tid;
        const int r = c >> 7;
        const int o = (c & 127) << 4;
        const f32x4 v = *reinterpret_cast<const f32x4*>(
            (const char*)(src + (size_t)(row0 + r) * HD) + o);
        *reinterpret_cast<f32x4*>(lds + r * 2048 + (o ^ ((r & 7) << 4))) = v;
    }
}

// ---------------------------------------------------------------------------
// gemmLG: 16x16 frag, K=1024; A from swizzled LDS, B from global with
// explicit 8-deep double-buffered prefetch (all indices compile-time ->
// registers, ~64 VGPR of B in flight). 2-way acc split breaks MFMA chain.
// ---------------------------------------------------------------------------
static __device__ __forceinline__ f32x4 gemmLG(const char* ldsA, int rlbase,
                                               int kgoff, int aswz,
                                               const short* __restrict__ bp) {
    f32x4 acc0 = {0.f,0.f,0.f,0.f}, acc1 = {0.f,0.f,0.f,0.f};
    short8 b0[8], b1[8];
#pragma unroll
    for (int j = 0; j < 8; ++j) b0[j] = ld8(bp + j * 32);
#pragma unroll
    for (int c = 0; c < 4; ++c) {                    // 4 chunks x (8 x K=32)
        if (c < 3) {
            short8* nxt = (c & 1) ? b0 : b1;         // c is compile-time
#pragma unroll
            for (int j = 0; j < 8; ++j) nxt[j] = ld8(bp + (c + 1) * 256 + j * 32);
        }
        const short8* cur = (c & 1) ? b1 : b0;
#pragma unroll
        for (int j = 0; j < 8; ++j) {
            const short8 a = *reinterpret_cast<const short8*>(
                ldsA + rlbase + ((kgoff + ((c * 256 + j * 32) << 1)) ^ aswz));
            if (j & 1) acc1 = mfma16(a, cur[j], acc1);
            else       acc0 = mfma16(a, cur[j], acc0);
        }
    }
    return acc0 + acc1;
}

// ---------------------------------------------------------------------------
// step_fused: one skewed phase k (R8-proven structure + pipelined gemms).
// bid<128: layer0 -> h0(k);  bid>=128: layer1 -> h1(k-1).
// Block: 32 rows x 64 cols, 512 thr, 64KB LDS.
// ---------------------------------------------------------------------------
__global__ __launch_bounds__(512) void step_fused(
    int k, const short* __restrict__ xbf,
    const short* __restrict__ WfoldT, const float* __restrict__ bf0,
    const short* __restrict__ WhhT0, const short* __restrict__ WihT1,
    const short* __restrict__ WhhT1, const float* __restrict__ bf1,
    const short* __restrict__ h0prev, short* __restrict__ h0cur,
    const short* __restrict__ h1prev, short* __restrict__ h1cur,
    short* __restrict__ Hbuf) {

    extern __shared__ char lds[];                // 64 KB

    const int bid   = blockIdx.x;
    const int layer = bid >> 7;
    const int lb    = bid & 127;
    const int rt    = lb >> 4;
    const int ct    = lb & 15;
    const int w     = threadIdx.x >> 6;
    const int mh    = w & 1;
    const int nq    = w >> 1;
    const int l     = threadIdx.x & 63;
    const int lr    = l & 15, kg = l >> 4;
    const int row0  = rt * 32;
    const int m0    = row0 + mh * 16;
    const int n0    = ct * 64 + nq * 16;
    const int col   = n0 + lr;
    const int rb    = m0 + kg * 4;
    const int rl    = mh * 16 + lr;
    const int rlbase = rl * 2048;
    const int kgoff  = kg * 16;
    const int aswz   = (rl & 7) << 4;

    if (layer == 0) {
        if (k >= S - 1) return;
        f32x4 acc = {0.f, 0.f, 0.f, 0.f};
        const short* xp = xbf + ((size_t)(m0 + lr) * S + k) * F + kg * 8;
        const short* wf = WfoldT + (size_t)col * F + kg * 8;
        acc = mfma16(ld8(xp),      ld8(wf),      acc);
        acc = mfma16(ld8(xp + 32), ld8(wf + 32), acc);
        if (k > 0) {
            stageA(lds, h0prev, row0);
            __syncthreads();
            acc += gemmLG(lds, rlbase, kgoff, aswz,
                          WhhT0 + (size_t)col * HD + kg * 8);
        }
        const float bb = bf0[col];
#pragma unroll
        for (int r = 0; r < 4; ++r)
            h0cur[(size_t)(rb + r) * HD + col] = f2bf(tanhf(acc[r] + bb));
    } else {
        if (k < 1) return;
        const int t = k - 1;
        stageA(lds, h0prev, row0);               // h0(k-1)
        __syncthreads();
        // T14 async-stage: issue h1(t-1) staging loads BEFORE gemm1's MFMAs;
        // held in registers, written to LDS after the barrier.
        f32x4 pre[8];
        if (t > 0) {
#pragma unroll
            for (int it = 0; it < 8; ++it) {
                const int c2 = it * 512 + (int)threadIdx.x;
                const int r = c2 >> 7, o = (c2 & 127) << 4;
                pre[it] = *reinterpret_cast<const f32x4*>(
                    (const char*)(h1prev + (size_t)(row0 + r) * HD) + o);
            }
        }
        f32x4 acc = gemmLG(lds, rlbase, kgoff, aswz,
                           WihT1 + (size_t)col * HD + kg * 8);
        if (t > 0) {
            __syncthreads();                     // gemm1 LDS reads done
#pragma unroll
            for (int it = 0; it < 8; ++it) {
                const int c2 = it * 512 + (int)threadIdx.x;
                const int r = c2 >> 7, o = (c2 & 127) << 4;
                *reinterpret_cast<f32x4*>(lds + r * 2048 + (o ^ ((r & 7) << 4)))
                    = pre[it];
            }
            __syncthreads();
            acc += gemmLG(lds, rlbase, kgoff, aswz,
                          WhhT1 + (size_t)col * HD + kg * 8);
        }
        const float bb = bf1[col];
#pragma unroll
        for (int r = 0; r < 4; ++r) {
            const float v = tanhf(acc[r] + bb);
            h1cur[(size_t)(rb + r) * HD + col] = f2bf(v);
            if (t >= TSTART) {
                const float rv = v > 0.f ? v : 0.f;
                Hbuf[((size_t)(rb + r) * PRED + (t - TSTART)) * HD + col] = f2bf(rv);
            }
        }
    }
}

// ---------------------------------------------------------------------------
// outgemm: out = H(relu'd) @ WoT + bo ; M=12288, N=64, K=1024.
// ---------------------------------------------------------------------------
__global__ __launch_bounds__(256) void outgemm(
    const short* __restrict__ Hbuf, const short* __restrict__ WoT,
    const float* __restrict__ bo, float* __restrict__ out) {
    const int w = threadIdx.x >> 6, l = threadIdx.x & 63;
    const int lr = l & 15, kg = l >> 4;
    const int m0 = blockIdx.x * 64 + w * 16;
    const int arow = m0 + lr;

    f32x4 acc[4] = {{0.f,0.f,0.f,0.f},{0.f,0.f,0.f,0.f},
                    {0.f,0.f,0.f,0.f},{0.f,0.f,0.f,0.f}};
    const short* ap = Hbuf + (size_t)arow * HD + kg * 8;
    const short* bp = WoT + (size_t)lr * HD + kg * 8;
#pragma unroll 4
    for (int k0 = 0; k0 < HD; k0 += 32) {
        const short8 a = ld8(ap + k0);
#pragma unroll
        for (int c = 0; c < 4; ++c)
            acc[c] = mfma16(a, ld8(bp + (size_t)c * 16 * HD + k0), acc[c]);
    }
    const int rb = m0 + kg * 4;
#pragma unroll
    for (int c = 0; c < 4; ++c) {
        const float bbv = bo[c * 16 + lr];
#pragma unroll
        for (int r = 0; r < 4; ++r)
            out[(size_t)(rb + r) * F + c * 16 + lr] = acc[c][r] + bbv;
    }
}

// ---------------------------------------------------------------------------
extern "C" void kernel_launch(void* const* d_in, const int* in_sizes, int n_in,
                              void* d_out, int out_size, void* d_ws, size_t ws_size,
                              hipStream_t stream) {
    const float* x   = (const float*)d_in[0];
    const float* Wh  = (const float*)d_in[1];
    const float* bh  = (const float*)d_in[2];
    const float* Wih = (const float*)d_in[3];
    const float* Whh = (const float*)d_in[4];
    const float* bih = (const float*)d_in[5];
    const float* bhh = (const float*)d_in[6];
    const float* Wo  = (const float*)d_in[7];
    const float* bo  = (const float*)d_in[8];
    float* out = (float*)d_out;

    char* p = (char*)d_ws;
    float* Wfold  = (float*)p; p += (size_t)F * HD * 4;
    float* bf0    = (float*)p; p += HD * 4;
    float* bf1    = (float*)p; p += HD * 4;
    short* WfoldT = (short*)p; p += (size_t)HD * F * 2;
    short* WhhT0  = (short*)p; p += (size_t)HD * HD * 2;
    short* WihT1  = (short*)p; p += (size_t)HD * HD * 2;
    short* WhhT1  = (short*)p; p += (size_t)HD * HD * 2;
    short* WoT    = (short*)p; p += (size_t)F * HD * 2;
    short* h0b0   = (short*)p; p += (size_t)B * HD * 2;
    short* h0b1   = (short*)p; p += (size_t)B * HD * 2;
    short* h1b0   = (short*)p; p += (size_t)B * HD * 2;
    short* h1b1   = (short*)p; p += (size_t)B * HD * 2;
    short* Hbuf   = (short*)p; p += (size_t)B * PRED * HD * 2;
    short* xbf    = (short*)p; p += (size_t)B * S * F * 2;

    fold_kernel<<<256, 256, 0, stream>>>(Wh, Wih, Wfold);
    bias_kernel<<<4, 256, 0, stream>>>(bh, Wih, bih, bhh, bf0, bf1);
    transpose_cast<<<16, 256, 0, stream>>>(Wfold, WfoldT, F, HD);
    transpose_cast<<<256, 256, 0, stream>>>(Whh, WhhT0, HD, HD);
    transpose_cast<<<256, 256, 0, stream>>>(Wih + (size_t)HD * HD, WihT1, HD, HD);
    transpose_cast<<<256, 256, 0, stream>>>(Whh + (size_t)HD * HD, WhhT1, HD, HD);
    transpose_cast<<<16, 256, 0, stream>>>(Wo, WoT, HD, F);
    xcast<<<(B * S * F) / (256 * 4), 256, 0, stream>>>(x, xbf);

    short* h0b[2] = {h0b0, h0b1};
    short* h1b[2] = {h1b0, h1b1};
    for (int k = 0; k < S; ++k) {
        step_fused<<<256, 512, 65536, stream>>>(
            k, xbf, WfoldT, bf0, WhhT0, WihT1, WhhT1, bf1,
            h0b[(k + 1) & 1], h0b[k & 1],
            h1b[k & 1],       h1b[(k + 1) & 1],
            Hbuf);
    }
    outgemm<<<192, 256, 0, stream>>>(Hbuf, WoT, bo, out);
}

// Round 10
// 3599.300 us; speedup vs baseline: 1.0701x; 1.0701x over previous
//
#include <hip/hip_runtime.h>
#include <hip/hip_bf16.h>

#define B    256
#define S    192
#define F    64
#define HD   1024
#define PRED 48
#define TSTART (S - 1 - PRED)   // 143
#define NSLOT 48

typedef __attribute__((ext_vector_type(8))) short short8;
typedef __attribute__((ext_vector_type(4))) float f32x4;
typedef unsigned int u32;
typedef unsigned long long u64;

static __device__ __forceinline__ short f2bf(float f) {
    __hip_bfloat16 h = __float2bfloat16(f);
    return *reinterpret_cast<short*>(&h);
}
static __device__ __forceinline__ f32x4 mfma16(short8 a, short8 b, f32x4 c) {
    return __builtin_amdgcn_mfma_f32_16x16x32_bf16(a, b, c, 0, 0, 0);
}
static __device__ __forceinline__ short8 ld8(const short* p) {
    return *reinterpret_cast<const short8*>(p);
}
// sc1 write-through store: data lands at MALL (device coherence point).
// R4/R7-proven. Readers use plain cached loads on 48-slot-rotated (fresh)
// addresses -> never-stale, weights/x stay L2-resident (no invalidation).
static __device__ __forceinline__ void st_state(short* p, short v) {
    __hip_atomic_store(p, v, __ATOMIC_RELAXED, __HIP_MEMORY_SCOPE_AGENT);
}

// ---------------------------------------------------------------------------
// prep kernels
// ---------------------------------------------------------------------------
__global__ void fold_kernel(const float* __restrict__ Wh,
                            const float* __restrict__ Wih0,
                            float* __restrict__ Wfold) {
    const int n = (blockIdx.x & 3) * 256 + threadIdx.x;
    const int f = blockIdx.x >> 2;
    float a = 0.f;
#pragma unroll 16
    for (int k = 0; k < HD; ++k)
        a += Wh[f * HD + k] * Wih0[(size_t)k * HD + n];
    Wfold[f * HD + n] = a;
}

// parallel-K bias: 64 blocks x 256 thr; thread = (n-lane 0..15, kchunk 0..15)
__global__ void bias_kernel(const float* __restrict__ bh,
                            const float* __restrict__ Wih0,
                            const float* __restrict__ bih,
                            const float* __restrict__ bhh,
                            float* __restrict__ bf0,
                            float* __restrict__ bf1) {
    __shared__ float red[256];
    const int nl = threadIdx.x & 15;
    const int kc = threadIdx.x >> 4;
    const int n  = blockIdx.x * 16 + nl;
    float a = 0.f;
#pragma unroll 8
    for (int k = kc * 64; k < kc * 64 + 64; ++k)
        a += bh[k] * Wih0[(size_t)k * HD + n];
    red[threadIdx.x] = a;
    __syncthreads();
    if (kc == 0) {
        float s = 0.f;
#pragma unroll
        for (int j = 0; j < 16; ++j) s += red[j * 16 + nl];
        bf0[n] = s + bih[n] + bhh[n];
        bf1[n] = bih[HD + n] + bhh[HD + n];
    }
}

__global__ void transpose_cast(const float* __restrict__ src,
                               short* __restrict__ dst, int K, int N) {
    __shared__ float tile[64][65];
    const int nk = K >> 6;
    const int bk = blockIdx.x % nk;
    const int bn = blockIdx.x / nk;
    const int i  = threadIdx.x;
    {
        const int c4 = (i & 15) * 4;
        for (int it = 0; it < 4; ++it) {
            const int k = (i >> 4) + it * 16;
            const float4 v = *reinterpret_cast<const float4*>(
                &src[(size_t)(bk * 64 + k) * N + bn * 64 + c4]);
            tile[k][c4 + 0] = v.x; tile[k][c4 + 1] = v.y;
            tile[k][c4 + 2] = v.z; tile[k][c4 + 3] = v.w;
        }
    }
    __syncthreads();
    {
        const int n  = i >> 2;
        const int kb = (i & 3) * 16;
        short* dp = &dst[(size_t)(bn * 64 + n) * K + bk * 64 + kb];
#pragma unroll
        for (int j = 0; j < 16; ++j) dp[j] = f2bf(tile[kb + j][n]);
    }
}

__global__ void xcast(const float* __restrict__ x, short* __restrict__ xb) {
    const size_t i = ((size_t)blockIdx.x * 256 + threadIdx.x) * 4;
    const float4 v = *reinterpret_cast<const float4*>(&x[i]);
    short4 o;
    o.x = f2bf(v.x); o.y = f2bf(v.y); o.z = f2bf(v.z); o.w = f2bf(v.w);
    *reinterpret_cast<short4*>(&xb[i]) = o;
}

// ---------------------------------------------------------------------------
// stageA: 32 rows x 1024 bf16 -> 64KB LDS, XOR-swizzled (R8-proven).
// ---------------------------------------------------------------------------
static __device__ __forceinline__ void stageA(char* lds, const short* __restrict__ src,
                                              int row0) {
    const int tid = threadIdx.x;
#pragma unroll
    for (int it = 0; it < 8; ++it) {
        const int c = it * 512 + tid;
        const int r = c >> 7;
        const int o = (c & 127) << 4;
        const f32x4 v = *reinterpret_cast<const f32x4*>(
            (const char*)(src + (size_t)(row0 + r) * HD) + o);
        *reinterpret_cast<f32x4*>(lds + r * 2048 + (o ^ ((r & 7) << 4))) = v;
    }
}

// ---------------------------------------------------------------------------
// gemmLG: 16x16 frag, K=1024; A from swizzled LDS, B from global with 8-deep
// double-buffered prefetch (compile-time indices -> registers). (R9)
// ---------------------------------------------------------------------------
static __device__ __forceinline__ f32x4 gemmLG(const char* ldsA, int rlbase,
                                               int kgoff, int aswz,
                                               const short* __restrict__ bp) {
    f32x4 acc0 = {0.f,0.f,0.f,0.f}, acc1 = {0.f,0.f,0.f,0.f};
    short8 b0[8], b1[8];
#pragma unroll
    for (int j = 0; j < 8; ++j) b0[j] = ld8(bp + j * 32);
#pragma unroll
    for (int c = 0; c < 4; ++c) {
        if (c < 3) {
            short8* nxt = (c & 1) ? b0 : b1;
#pragma unroll
            for (int j = 0; j < 8; ++j) nxt[j] = ld8(bp + (c + 1) * 256 + j * 32);
        }
        const short8* cur = (c & 1) ? b1 : b0;
#pragma unroll
        for (int j = 0; j < 8; ++j) {
            const short8 a = *reinterpret_cast<const short8*>(
                ldsA + rlbase + ((kgoff + ((c * 256 + j * 32) << 1)) ^ aswz));
            if (j & 1) acc1 = mfma16(a, cur[j], acc1);
            else       acc0 = mfma16(a, cur[j], acc0);
        }
    }
    return acc0 + acc1;
}

// ---------------------------------------------------------------------------
// Two-level grid barrier: 16 leaf lines (bid&15; 16 arrivals each, parallel
// across lines) -> root line (16 arrivals) -> epoch broadcast. All relaxed
// agent-scope; __syncthreads drains sc1 stores (vmcnt 0) before arrival.
// No placement assumptions: leaf membership is by bid, grid is exactly 256.
// ---------------------------------------------------------------------------
static __device__ __forceinline__ void gridbar2(u32* leaf, u32* root, u32* epoch,
                                                int bid, u32 target) {
    __syncthreads();
    if (threadIdx.x == 0) {
        u32* lf = leaf + (bid & 15) * 32;          // 128B-separated lines
        const u32 lo = __hip_atomic_fetch_add(lf, 1u, __ATOMIC_RELAXED,
                                              __HIP_MEMORY_SCOPE_AGENT);
        if (lo == target * 16u - 1u) {
            const u32 ro = __hip_atomic_fetch_add(root, 1u, __ATOMIC_RELAXED,
                                                  __HIP_MEMORY_SCOPE_AGENT);
            if (ro == target * 16u - 1u)
                __hip_atomic_store(epoch, target, __ATOMIC_RELAXED,
                                   __HIP_MEMORY_SCOPE_AGENT);
        }
        while (__hip_atomic_load(epoch, __ATOMIC_RELAXED,
                                 __HIP_MEMORY_SCOPE_AGENT) < target)
            __builtin_amdgcn_s_sleep(1);
    }
    __syncthreads();
}

// ---------------------------------------------------------------------------
// Persistent skewed recurrence. 256 blocks x 512 thr, 64KB LDS (cooperative).
// Phase k: bid<128 (layer0) -> h0(k) [k<191]; bid>=128 (layer1) -> h1(k-1)
// [k>=1]. Body = R8/R9-proven step_fused. State in 48-slot rotating history:
// sc1 write-through stores, plain cached reads (fresh addresses, R7-proven).
// Weights/x never invalidated -> L2-hot all 192 phases. One barrier/phase.
// ---------------------------------------------------------------------------
__global__ __launch_bounds__(512, 1) void rnn_pers(
    const short* __restrict__ xbf,
    const short* __restrict__ WfoldT, const float* __restrict__ bf0,
    const short* __restrict__ WhhT0, const short* __restrict__ WihT1,
    const short* __restrict__ WhhT1, const float* __restrict__ bf1,
    short* h0h, short* h1h, u32* leaf, u32* root, u32* epoch) {

    extern __shared__ char lds[];                // 64 KB

    const int bid   = blockIdx.x;
    const int layer = bid >> 7;
    const int lb    = bid & 127;
    const int rt    = lb >> 4;
    const int ct    = lb & 15;
    const int w     = threadIdx.x >> 6;
    const int mh    = w & 1;
    const int nq    = w >> 1;
    const int l     = threadIdx.x & 63;
    const int lr    = l & 15, kg = l >> 4;
    const int row0  = rt * 32;
    const int m0    = row0 + mh * 16;
    const int n0    = ct * 64 + nq * 16;
    const int col   = n0 + lr;
    const int rb    = m0 + kg * 4;
    const int rl    = mh * 16 + lr;
    const int rlbase = rl * 2048;
    const int kgoff  = kg * 16;
    const int aswz   = (rl & 7) << 4;

    const float bb = (layer ? bf1 : bf0)[col];

    for (int k = 0; k < S; ++k) {
        const short* h0prev = h0h + (size_t)((k + NSLOT - 1) % NSLOT) * B * HD;
        if (layer == 0) {
            if (k < S - 1) {
                f32x4 acc = {0.f, 0.f, 0.f, 0.f};
                const short* xp = xbf + ((size_t)(m0 + lr) * S + k) * F + kg * 8;
                const short* wf = WfoldT + (size_t)col * F + kg * 8;
                acc = mfma16(ld8(xp),      ld8(wf),      acc);
                acc = mfma16(ld8(xp + 32), ld8(wf + 32), acc);
                if (k > 0) {
                    stageA(lds, h0prev, row0);
                    __syncthreads();
                    acc += gemmLG(lds, rlbase, kgoff, aswz,
                                  WhhT0 + (size_t)col * HD + kg * 8);
                }
                short* hd = h0h + (size_t)(k % NSLOT) * B * HD;
#pragma unroll
                for (int r = 0; r < 4; ++r)
                    st_state(&hd[(size_t)(rb + r) * HD + col],
                             f2bf(tanhf(acc[r] + bb)));
            }
        } else {
            if (k >= 1) {
                const int t = k - 1;
                const short* h1prev = h1h + (size_t)((t + NSLOT - 1) % NSLOT) * B * HD;
                stageA(lds, h0prev, row0);       // h0(k-1), barrier-separated
                __syncthreads();
                f32x4 pre[8];                    // T14 async-stage h1(t-1)
                if (t > 0) {
#pragma unroll
                    for (int it = 0; it < 8; ++it) {
                        const int c2 = it * 512 + (int)threadIdx.x;
                        const int r = c2 >> 7, o = (c2 & 127) << 4;
                        pre[it] = *reinterpret_cast<const f32x4*>(
                            (const char*)(h1prev + (size_t)(row0 + r) * HD) + o);
                    }
                }
                f32x4 acc = gemmLG(lds, rlbase, kgoff, aswz,
                                   WihT1 + (size_t)col * HD + kg * 8);
                if (t > 0) {
                    __syncthreads();             // gemm1 LDS reads done
#pragma unroll
                    for (int it = 0; it < 8; ++it) {
                        const int c2 = it * 512 + (int)threadIdx.x;
                        const int r = c2 >> 7, o = (c2 & 127) << 4;
                        *reinterpret_cast<f32x4*>(
                            lds + r * 2048 + (o ^ ((r & 7) << 4))) = pre[it];
                    }
                    __syncthreads();
                    acc += gemmLG(lds, rlbase, kgoff, aswz,
                                  WhhT1 + (size_t)col * HD + kg * 8);
                }
                short* hd = h1h + (size_t)(t % NSLOT) * B * HD;
#pragma unroll
                for (int r = 0; r < 4; ++r)
                    st_state(&hd[(size_t)(rb + r) * HD + col],
                             f2bf(tanhf(acc[r] + bb)));
            }
        }
        if (k < S - 1) gridbar2(leaf, root, epoch, bid, (u32)(k + 1));
    }
}

// ---------------------------------------------------------------------------
// outgemm: out[b][p][f] = relu(h1(143+p)[b]) @ WoT + bo, reading history
// slots (bijective (143+p)%48; slots t>=143 never overwritten). R7-proven.
// ---------------------------------------------------------------------------
__global__ __launch_bounds__(256) void outgemm(
    const short* __restrict__ h1h, const short* __restrict__ WoT,
    const float* __restrict__ bo, float* __restrict__ out) {
    const int w = threadIdx.x >> 6, l = threadIdx.x & 63;
    const int lr = l & 15, kg = l >> 4;
    const int m0 = blockIdx.x * 64 + w * 16;
    const int arow = m0 + lr;                 // b*48+p
    const u32 bidx = (u32)arow / 48u;
    const u32 p    = (u32)arow % 48u;
    const u32 slot = (143u + p) % 48u;

    f32x4 acc[4] = {{0.f,0.f,0.f,0.f},{0.f,0.f,0.f,0.f},
                    {0.f,0.f,0.f,0.f},{0.f,0.f,0.f,0.f}};
    const short* ap = h1h + ((size_t)slot * B + bidx) * HD + kg * 8;
    const short* bp = WoT + (size_t)lr * HD + kg * 8;
#pragma unroll 4
    for (int k0 = 0; k0 < HD; k0 += 32) {
        short8 a = ld8(ap + k0);
#pragma unroll
        for (int j = 0; j < 8; ++j) a[j] = (a[j] < 0) ? (short)0 : a[j];  // relu
#pragma unroll
        for (int c = 0; c < 4; ++c)
            acc[c] = mfma16(a, ld8(bp + (size_t)c * 16 * HD + k0), acc[c]);
    }
    const int rb = m0 + kg * 4;
#pragma unroll
    for (int c = 0; c < 4; ++c) {
        const float bbv = bo[c * 16 + lr];
#pragma unroll
        for (int r = 0; r < 4; ++r)
            out[(size_t)(rb + r) * F + c * 16 + lr] = acc[c][r] + bbv;
    }
}

// ---------------------------------------------------------------------------
extern "C" void kernel_launch(void* const* d_in, const int* in_sizes, int n_in,
                              void* d_out, int out_size, void* d_ws, size_t ws_size,
                              hipStream_t stream) {
    const float* x   = (const float*)d_in[0];
    const float* Wh  = (const float*)d_in[1];
    const float* bh  = (const float*)d_in[2];
    const float* Wih = (const float*)d_in[3];
    const float* Whh = (const float*)d_in[4];
    const float* bih = (const float*)d_in[5];
    const float* bhh = (const float*)d_in[6];
    const float* Wo  = (const float*)d_in[7];
    const float* bo  = (const float*)d_in[8];
    float* out = (float*)d_out;

    char* p = (char*)d_ws;
    float* Wfold  = (float*)p; p += (size_t)F * HD * 4;
    float* bf0    = (float*)p; p += HD * 4;
    float* bf1    = (float*)p; p += HD * 4;
    short* WfoldT = (short*)p; p += (size_t)HD * F * 2;
    short* WhhT0  = (short*)p; p += (size_t)HD * HD * 2;
    short* WihT1  = (short*)p; p += (size_t)HD * HD * 2;
    short* WhhT1  = (short*)p; p += (size_t)HD * HD * 2;
    short* WoT    = (short*)p; p += (size_t)F * HD * 2;
    short* h0h    = (short*)p; p += (size_t)NSLOT * B * HD * 2;   // 24 MB
    short* h1h    = (short*)p; p += (size_t)NSLOT * B * HD * 2;   // 24 MB
    short* xbf    = (short*)p; p += (size_t)B * S * F * 2;
    u32*   sync   = (u32*)p;  p += 4096;
    // sync: leaf[16*32] (2048B) | root (+2048) | epoch (+2176)

    hipMemsetAsync(sync, 0, 4096, stream);

    fold_kernel<<<256, 256, 0, stream>>>(Wh, Wih, Wfold);
    bias_kernel<<<64, 256, 0, stream>>>(bh, Wih, bih, bhh, bf0, bf1);
    transpose_cast<<<16, 256, 0, stream>>>(Wfold, WfoldT, F, HD);
    transpose_cast<<<256, 256, 0, stream>>>(Whh, WhhT0, HD, HD);
    transpose_cast<<<256, 256, 0, stream>>>(Wih + (size_t)HD * HD, WihT1, HD, HD);
    transpose_cast<<<256, 256, 0, stream>>>(Whh + (size_t)HD * HD, WhhT1, HD, HD);
    transpose_cast<<<16, 256, 0, stream>>>(Wo, WoT, HD, F);
    xcast<<<(B * S * F) / (256 * 4), 256, 0, stream>>>(x, xbf);

    u32* leaf  = sync;
    u32* root  = sync + 512;
    u32* epoch = sync + 544;
    void* args[] = {
        (void*)&xbf, (void*)&WfoldT, (void*)&bf0, (void*)&WhhT0,
        (void*)&WihT1, (void*)&WhhT1, (void*)&bf1,
        (void*)&h0h, (void*)&h1h, (void*)&leaf, (void*)&root, (void*)&epoch
    };
    hipLaunchCooperativeKernel((void*)rnn_pers, dim3(256), dim3(512),
                               args, 65536, stream);

    outgemm<<<192, 256, 0, stream>>>(h1h, WoT, bo, out);
}

// Round 11
// 2193.509 us; speedup vs baseline: 1.7560x; 1.6409x over previous
//
#include <hip/hip_runtime.h>
#include <hip/hip_bf16.h>

#define B    256
#define S    192
#define F    64
#define HD   1024
#define PRED 48
#define TSTART (S - 1 - PRED)   // 143
#define NSLOT 48

typedef __attribute__((ext_vector_type(8))) short short8;
typedef __attribute__((ext_vector_type(4))) float f32x4;
typedef unsigned int u32;

static __device__ __forceinline__ short f2bf(float f) {
    __hip_bfloat16 h = __float2bfloat16(f);
    return *reinterpret_cast<short*>(&h);
}
static __device__ __forceinline__ f32x4 mfma16(short8 a, short8 b, f32x4 c) {
    return __builtin_amdgcn_mfma_f32_16x16x32_bf16(a, b, c, 0, 0, 0);
}
static __device__ __forceinline__ short8 ld8(const short* p) {
    return *reinterpret_cast<const short8*>(p);
}
// sc1 write-through store (lands at MALL, device coherence point). R4/R7/R10-
// proven. Readers use plain cached loads on 48-slot-rotated fresh addresses;
// stale-L2 survival is precluded by ~190MB of fill churn per 47 phases per
// 4MB L2 (empirically validated R7/R10: absmax identical to fp32 path).
static __device__ __forceinline__ void st_state(short* p, short v) {
    __hip_atomic_store(p, v, __ATOMIC_RELAXED, __HIP_MEMORY_SCOPE_AGENT);
}
static __device__ __forceinline__ u32 ld_flag(const u32* p) {
    return __hip_atomic_load(p, __ATOMIC_RELAXED, __HIP_MEMORY_SCOPE_AGENT);
}
static __device__ __forceinline__ void st_flag(u32* p, u32 v) {
    __hip_atomic_store(p, v, __ATOMIC_RELAXED, __HIP_MEMORY_SCOPE_AGENT);
}

// ---------------------------------------------------------------------------
// prep kernels (proven)
// ---------------------------------------------------------------------------
__global__ void fold_kernel(const float* __restrict__ Wh,
                            const float* __restrict__ Wih0,
                            float* __restrict__ Wfold) {
    const int n = (blockIdx.x & 3) * 256 + threadIdx.x;
    const int f = blockIdx.x >> 2;
    float a = 0.f;
#pragma unroll 16
    for (int k = 0; k < HD; ++k)
        a += Wh[f * HD + k] * Wih0[(size_t)k * HD + n];
    Wfold[f * HD + n] = a;
}

__global__ void bias_kernel(const float* __restrict__ bh,
                            const float* __restrict__ Wih0,
                            const float* __restrict__ bih,
                            const float* __restrict__ bhh,
                            float* __restrict__ bf0,
                            float* __restrict__ bf1) {
    __shared__ float red[256];
    const int nl = threadIdx.x & 15;
    const int kc = threadIdx.x >> 4;
    const int n  = blockIdx.x * 16 + nl;
    float a = 0.f;
#pragma unroll 8
    for (int k = kc * 64; k < kc * 64 + 64; ++k)
        a += bh[k] * Wih0[(size_t)k * HD + n];
    red[threadIdx.x] = a;
    __syncthreads();
    if (kc == 0) {
        float s = 0.f;
#pragma unroll
        for (int j = 0; j < 16; ++j) s += red[j * 16 + nl];
        bf0[n] = s + bih[n] + bhh[n];
        bf1[n] = bih[HD + n] + bhh[HD + n];
    }
}

__global__ void transpose_cast(const float* __restrict__ src,
                               short* __restrict__ dst, int K, int N) {
    __shared__ float tile[64][65];
    const int nk = K >> 6;
    const int bk = blockIdx.x % nk;
    const int bn = blockIdx.x / nk;
    const int i  = threadIdx.x;
    {
        const int c4 = (i & 15) * 4;
        for (int it = 0; it < 4; ++it) {
            const int k = (i >> 4) + it * 16;
            const float4 v = *reinterpret_cast<const float4*>(
                &src[(size_t)(bk * 64 + k) * N + bn * 64 + c4]);
            tile[k][c4 + 0] = v.x; tile[k][c4 + 1] = v.y;
            tile[k][c4 + 2] = v.z; tile[k][c4 + 3] = v.w;
        }
    }
    __syncthreads();
    {
        const int n  = i >> 2;
        const int kb = (i & 3) * 16;
        short* dp = &dst[(size_t)(bn * 64 + n) * K + bk * 64 + kb];
#pragma unroll
        for (int j = 0; j < 16; ++j) dp[j] = f2bf(tile[kb + j][n]);
    }
}

__global__ void xcast(const float* __restrict__ x, short* __restrict__ xb) {
    const size_t i = ((size_t)blockIdx.x * 256 + threadIdx.x) * 4;
    const float4 v = *reinterpret_cast<const float4*>(&x[i]);
    short4 o;
    o.x = f2bf(v.x); o.y = f2bf(v.y); o.z = f2bf(v.z); o.w = f2bf(v.w);
    *reinterpret_cast<short4*>(&xb[i]) = o;
}

// ---------------------------------------------------------------------------
// Conflict-free LDS layout (k-chunk-major):
//   addr(row r 0..31, kchunk kc 0..31, kg 0..3) = kc*2048 + r*64 + kg*16
// stage: thread writes LDS at idx*16 (linear -> 0 write conflicts);
// gemm read: wave's 64 lanes (lr,kg) read 1024 contiguous bytes per chunk
// (lr*64+kg*16 covers 0..1008 exactly once) -> 0 read conflicts.
// ---------------------------------------------------------------------------
static __device__ __forceinline__ void stageA(char* lds, const short* __restrict__ src,
                                              int row0) {
    const int tid = threadIdx.x;
#pragma unroll
    for (int it = 0; it < 8; ++it) {
        const int idx = it * 512 + tid;
        const int r   = (idx >> 2) & 31;
        const int off = ((idx >> 7) << 6) + ((idx & 3) << 4);   // kc*64+kg*16
        const f32x4 v = *reinterpret_cast<const f32x4*>(
            (const char*)src + (size_t)(row0 + r) * 2048 + off);
        *reinterpret_cast<f32x4*>(lds + (idx << 4)) = v;
    }
}

// gemmLG: 16x16 frag, K=1024; A from LDS (ldsA = lds + mh*1024 + lr*64 +
// kg*16, stride 2048/chunk), B from global with 8-deep double-buffered
// prefetch (compile-time indices -> registers).
static __device__ __forceinline__ f32x4 gemmLG(const char* ldsA,
                                               const short* __restrict__ bp) {
    f32x4 acc0 = {0.f,0.f,0.f,0.f}, acc1 = {0.f,0.f,0.f,0.f};
    short8 b0[8], b1[8];
#pragma unroll
    for (int j = 0; j < 8; ++j) b0[j] = ld8(bp + j * 32);
#pragma unroll
    for (int c = 0; c < 4; ++c) {
        if (c < 3) {
            short8* nxt = (c & 1) ? b0 : b1;
#pragma unroll
            for (int j = 0; j < 8; ++j) nxt[j] = ld8(bp + (c + 1) * 256 + j * 32);
        }
        const short8* cur = (c & 1) ? b1 : b0;
#pragma unroll
        for (int j = 0; j < 8; ++j) {
            const short8 a = *reinterpret_cast<const short8*>(
                ldsA + (c * 8 + j) * 2048);
            if (j & 1) acc1 = mfma16(a, cur[j], acc1);
            else       acc0 = mfma16(a, cur[j], acc0);
        }
    }
    return acc0 + acc1;
}

// ---------------------------------------------------------------------------
// Persistent skewed recurrence with PER-GROUP flag sync (no global barrier).
// 256 blocks x 512 thr, 64KB LDS, cooperative (co-residency only).
// Group = rt (8 groups of 32 rows); groups are fully independent.
// bid<128: layer0 (rt,ct) computes h0(k) rows rt*32..+32, cols ct*64..+64.
// bid>=128: layer1 computes h1(k-1) same tile.
// Sync: block sets flag[rt][ct] = k+1 (sc1 store) after its phase-k stores
// drain (syncthreads -> vmcnt 0); consumers poll the 16 producer flags.
// L0 waits only on L0 peers (+ a lag bound on L1 for slot-rotation WAR).
// ---------------------------------------------------------------------------
__global__ __launch_bounds__(512, 1) void rnn_pers(
    const short* __restrict__ xbf,
    const short* __restrict__ WfoldT, const float* __restrict__ bf0,
    const short* __restrict__ WhhT0, const short* __restrict__ WihT1,
    const short* __restrict__ WhhT1, const float* __restrict__ bf1,
    short* h0h, short* h1h, u32* flags0, u32* flags1) {

    extern __shared__ char lds[];                // 64 KB

    const int bid   = blockIdx.x;
    const int layer = bid >> 7;
    const int lb    = bid & 127;
    const int rt    = lb >> 4;                   // 0..7
    const int ct    = lb & 15;                   // 0..15
    const int w     = threadIdx.x >> 6;
    const int mh    = w & 1;
    const int nq    = w >> 1;
    const int l     = threadIdx.x & 63;
    const int lr    = l & 15, kg = l >> 4;
    const int row0  = rt * 32;
    const int m0    = row0 + mh * 16;
    const int n0    = ct * 64 + nq * 16;
    const int col   = n0 + lr;
    const int rb    = m0 + kg * 4;
    const char* ldsA = lds + mh * 1024 + lr * 64 + kg * 16;

    const float bb = (layer ? bf1 : bf0)[col];
    u32* myflag = (layer ? flags1 : flags0) + (rt * 16 + ct) * 32;
    const int tid = threadIdx.x;

    if (layer == 0) {
        for (int k = 0; k < S - 1; ++k) {
            if (k > 0) {
                // wait: L0 peers done phase k-1; lag-bound on L1 (WAR, slot rot.)
                __syncthreads();
                if (tid < 16) {
                    const u32* f = flags0 + (rt * 16 + tid) * 32;
                    while (ld_flag(f) < (u32)k) __builtin_amdgcn_s_sleep(1);
                } else if (tid < 32 && k >= 46) {
                    const u32* f = flags1 + (rt * 16 + (tid - 16)) * 32;
                    while (ld_flag(f) < (u32)(k - 45)) __builtin_amdgcn_s_sleep(1);
                }
                __syncthreads();
                stageA(lds, h0h + (size_t)((k - 1) % NSLOT) * B * HD, row0);
                __syncthreads();
            }
            f32x4 acc = {0.f, 0.f, 0.f, 0.f};
            const short* xp = xbf + ((size_t)(m0 + lr) * S + k) * F + kg * 8;
            const short* wf = WfoldT + (size_t)col * F + kg * 8;
            acc = mfma16(ld8(xp),      ld8(wf),      acc);
            acc = mfma16(ld8(xp + 32), ld8(wf + 32), acc);
            if (k > 0)
                acc += gemmLG(ldsA, WhhT0 + (size_t)col * HD + kg * 8);
            short* hd = h0h + (size_t)(k % NSLOT) * B * HD;
#pragma unroll
            for (int r = 0; r < 4; ++r)
                st_state(&hd[(size_t)(rb + r) * HD + col],
                         f2bf(tanhf(acc[r] + bb)));
            __syncthreads();                      // drain sc1 stores (vmcnt 0)
            if (tid == 0) st_flag(myflag, (u32)(k + 1));
        }
    } else {
        if (tid == 0) st_flag(myflag, 1u);        // phase 0: no-op
        for (int k = 1; k < S; ++k) {
            const int t = k - 1;
            // wait: L0 peers done k-1 (h0(k-1)); L1 peers done k-1 (h1(k-2))
            __syncthreads();
            if (tid < 16) {
                const u32* f = flags0 + (rt * 16 + tid) * 32;
                while (ld_flag(f) < (u32)k) __builtin_amdgcn_s_sleep(1);
            } else if (tid < 32) {
                const u32* f = flags1 + (rt * 16 + (tid - 16)) * 32;
                while (ld_flag(f) < (u32)k) __builtin_amdgcn_s_sleep(1);
            }
            __syncthreads();
            stageA(lds, h0h + (size_t)((k - 1) % NSLOT) * B * HD, row0);
            f32x4 pre[8];                         // T14: h1(t-1) issue-early
            if (t > 0) {
                const char* hsrc = (const char*)(h1h
                    + (size_t)((t - 1) % NSLOT) * B * HD);
#pragma unroll
                for (int it = 0; it < 8; ++it) {
                    const int idx = it * 512 + tid;
                    const int r   = (idx >> 2) & 31;
                    const int off = ((idx >> 7) << 6) + ((idx & 3) << 4);
                    pre[it] = *reinterpret_cast<const f32x4*>(
                        hsrc + (size_t)(row0 + r) * 2048 + off);
                }
            }
            __syncthreads();
            f32x4 acc = gemmLG(ldsA, WihT1 + (size_t)col * HD + kg * 8);
            if (t > 0) {
                __syncthreads();                  // gemm1 LDS reads done
#pragma unroll
                for (int it = 0; it < 8; ++it) {
                    const int idx = it * 512 + tid;
                    *reinterpret_cast<f32x4*>(lds + (idx << 4)) = pre[it];
                }
                __syncthreads();
                acc += gemmLG(ldsA, WhhT1 + (size_t)col * HD + kg * 8);
            }
#pragma unroll
            for (int r = 0; r < 4; ++r)
                st_state(&h1h[(size_t)(t % NSLOT) * B * HD
                              + (size_t)(rb + r) * HD + col],
                         f2bf(tanhf(acc[r] + bb)));
            __syncthreads();                      // drain sc1 stores
            if (tid == 0) st_flag(myflag, (u32)(k + 1));
        }
    }
}

// ---------------------------------------------------------------------------
// outgemm: out[b][p][f] = relu(h1(143+p)[b]) @ WoT + bo, reading history
// slots ((143+p)%48, bijective). Kernel boundary gives coherence.
// ---------------------------------------------------------------------------
__global__ __launch_bounds__(256) void outgemm(
    const short* __restrict__ h1h, const short* __restrict__ WoT,
    const float* __restrict__ bo, float* __restrict__ out) {
    const int w = threadIdx.x >> 6, l = threadIdx.x & 63;
    const int lr = l & 15, kg = l >> 4;
    const int m0 = blockIdx.x * 64 + w * 16;
    const int arow = m0 + lr;                 // b*48+p
    const u32 bidx = (u32)arow / 48u;
    const u32 p    = (u32)arow % 48u;
    const u32 slot = (143u + p) % 48u;

    f32x4 acc[4] = {{0.f,0.f,0.f,0.f},{0.f,0.f,0.f,0.f},
                    {0.f,0.f,0.f,0.f},{0.f,0.f,0.f,0.f}};
    const short* ap = h1h + ((size_t)slot * B + bidx) * HD + kg * 8;
    const short* bp = WoT + (size_t)lr * HD + kg * 8;
#pragma unroll 4
    for (int k0 = 0; k0 < HD; k0 += 32) {
        short8 a = ld8(ap + k0);
#pragma unroll
        for (int j = 0; j < 8; ++j) a[j] = (a[j] < 0) ? (short)0 : a[j];  // relu
#pragma unroll
        for (int c = 0; c < 4; ++c)
            acc[c] = mfma16(a, ld8(bp + (size_t)c * 16 * HD + k0), acc[c]);
    }
    const int rb = m0 + kg * 4;
#pragma unroll
    for (int c = 0; c < 4; ++c) {
        const float bbv = bo[c * 16 + lr];
#pragma unroll
        for (int r = 0; r < 4; ++r)
            out[(size_t)(rb + r) * F + c * 16 + lr] = acc[c][r] + bbv;
    }
}

// ---------------------------------------------------------------------------
extern "C" void kernel_launch(void* const* d_in, const int* in_sizes, int n_in,
                              void* d_out, int out_size, void* d_ws, size_t ws_size,
                              hipStream_t stream) {
    const float* x   = (const float*)d_in[0];
    const float* Wh  = (const float*)d_in[1];
    const float* bh  = (const float*)d_in[2];
    const float* Wih = (const float*)d_in[3];
    const float* Whh = (const float*)d_in[4];
    const float* bih = (const float*)d_in[5];
    const float* bhh = (const float*)d_in[6];
    const float* Wo  = (const float*)d_in[7];
    const float* bo  = (const float*)d_in[8];
    float* out = (float*)d_out;

    char* p = (char*)d_ws;
    float* Wfold  = (float*)p; p += (size_t)F * HD * 4;
    float* bf0    = (float*)p; p += HD * 4;
    float* bf1    = (float*)p; p += HD * 4;
    short* WfoldT = (short*)p; p += (size_t)HD * F * 2;
    short* WhhT0  = (short*)p; p += (size_t)HD * HD * 2;
    short* WihT1  = (short*)p; p += (size_t)HD * HD * 2;
    short* WhhT1  = (short*)p; p += (size_t)HD * HD * 2;
    short* WoT    = (short*)p; p += (size_t)F * HD * 2;
    short* h0h    = (short*)p; p += (size_t)NSLOT * B * HD * 2;   // 24 MB
    short* h1h    = (short*)p; p += (size_t)NSLOT * B * HD * 2;   // 24 MB
    short* xbf    = (short*)p; p += (size_t)B * S * F * 2;
    u32*   sync   = (u32*)p;  p += 65536;
    // sync: flags0 = 128 flags x 128B (16KB) | flags1 at +16KB

    hipMemsetAsync(sync, 0, 65536, stream);

    fold_kernel<<<256, 256, 0, stream>>>(Wh, Wih, Wfold);
    bias_kernel<<<64, 256, 0, stream>>>(bh, Wih, bih, bhh, bf0, bf1);
    transpose_cast<<<16, 256, 0, stream>>>(Wfold, WfoldT, F, HD);
    transpose_cast<<<256, 256, 0, stream>>>(Whh, WhhT0, HD, HD);
    transpose_cast<<<256, 256, 0, stream>>>(Wih + (size_t)HD * HD, WihT1, HD, HD);
    transpose_cast<<<256, 256, 0, stream>>>(Whh + (size_t)HD * HD, WhhT1, HD, HD);
    transpose_cast<<<16, 256, 0, stream>>>(Wo, WoT, HD, F);
    xcast<<<(B * S * F) / (256 * 4), 256, 0, stream>>>(x, xbf);

    u32* flags0 = sync;
    u32* flags1 = sync + 4096;
    void* args[] = {
        (void*)&xbf, (void*)&WfoldT, (void*)&bf0, (void*)&WhhT0,
        (void*)&WihT1, (void*)&WhhT1, (void*)&bf1,
        (void*)&h0h, (void*)&h1h, (void*)&flags0, (void*)&flags1
    };
    hipLaunchCooperativeKernel((void*)rnn_pers, dim3(256), dim3(512),
                               args, 65536, stream);

    outgemm<<<192, 256, 0, stream>>>(h1h, WoT, bo, out);
}